// Round 9
// baseline (178.521 us; speedup 1.0000x reference)
//
#include <hip/hip_runtime.h>

typedef __attribute__((ext_vector_type(8))) short short8;
typedef __attribute__((ext_vector_type(4))) short s4v;
typedef __attribute__((ext_vector_type(2))) uint uint2v;
typedef __attribute__((ext_vector_type(4))) float floatx4;

#define CCH   256
#define QSCALE 0.17677669529663687f  // 32^-0.5
#define LOG2E  1.4426950408889634f

__device__ __forceinline__ unsigned short f2bf(float f) {
    unsigned u = __float_as_uint(f);
    u = u + 0x7fffu + ((u >> 16) & 1u);
    return (unsigned short)(u >> 16);
}

// pack two fp32 -> bf16x2 with round-half-up: (u+0x8000)>>16, fused via v_perm
__device__ __forceinline__ uint pk2bf(float a, float b) {
    uint ua = __float_as_uint(a) + 0x8000u;
    uint ub = __float_as_uint(b) + 0x8000u;
    return __builtin_amdgcn_perm(ub, ua, 0x07060302u);
}

__device__ __forceinline__ void gl_lds16(const void* g, void* l) {
    __builtin_amdgcn_global_load_lds((const __attribute__((address_space(1))) void*)g,
                                     (__attribute__((address_space(3))) void*)l, 16, 0, 0);
}

// token (w*512+n) -> flat spatial offset (*CCH) in x/out with +4 cyclic shift
__device__ __forceinline__ int spatial_off(int token) {
    int w = token >> 9, n = token & 511;
    int wh = w >> 4, ww = (w >> 2) & 3, wd = w & 3;
    int h1 = n >> 6, w1 = (n >> 3) & 7, d1 = n & 7;
    int gh = (wh * 8 + h1 + 4) & 31;
    int gw = (ww * 8 + w1 + 4) & 31;
    int gd = (wd * 8 + d1 + 4) & 31;
    return ((gh * 32 + gw) * 32 + gd) * CCH;
}

// ---------------- x (fp32, spatial) -> Xw (bf16, window-token order) ----------------
__global__ __launch_bounds__(256) void xconv(const float* __restrict__ x,
                                             ushort* __restrict__ Xw) {
    int tid = blockIdx.x * 256 + threadIdx.x;   // 1048576
    int token = tid >> 5, c8 = (tid & 31) * 8;
    const float* src = x + spatial_off(token) + c8;
    float4 a = *(const float4*)src;
    float4 b = *(const float4*)(src + 4);
    uint2v lo, hi;
    lo[0] = pk2bf(a.x, a.y);
    lo[1] = pk2bf(a.z, a.w);
    hi[0] = pk2bf(b.x, b.y);
    hi[1] = pk2bf(b.z, b.w);
    uint2v* dst = (uint2v*)(Xw + (size_t)token * 256 + c8);
    dst[0] = lo;
    dst[1] = hi;
}

// ---- weights fp32 -> bf16 (QSCALE*LOG2E folded into first 256 rows of Wq) ----
__global__ __launch_bounds__(256) void wconv(const float* __restrict__ Wq,
                                             const float* __restrict__ Wp,
                                             ushort* __restrict__ Wqb,
                                             ushort* __restrict__ Wpb) {
    int tid = blockIdx.x * 256 + threadIdx.x;   // 262144
    if (tid < 196608) {
        float s = (tid < 65536) ? (QSCALE * LOG2E) : 1.0f;
        Wqb[tid] = f2bf(Wq[tid] * s);
    } else {
        int i = tid - 196608;
        Wpb[i] = f2bf(Wp[i]);
    }
}

// -------- rel-pos pair table (pre-scaled by LOG2E):
// Up[head*3375 + idx] = pack(bf(rpb[idx]*log2e), bf(rpb[idx-1]*log2e)) ----
__global__ __launch_bounds__(256) void pair_prep(const float* __restrict__ rpb,
                                                 uint* __restrict__ Up) {
    int tid = blockIdx.x * 256 + threadIdx.x;   // 27000
    if (tid >= 27000) return;
    int head = tid / 3375, idx = tid - head * 3375;
    uint lo = f2bf(rpb[idx * 8 + head] * LOG2E);
    uint hi = f2bf(rpb[(idx > 0 ? idx - 1 : 0) * 8 + head] * LOG2E);
    Up[tid] = lo | (hi << 16);
}

// ---------------- MFMA GEMM: C[32768 x 768] = Xw @ Wqb^T -> Q/K/Vf ----------------
// V stored in K=16 MFMA A-fragment order per (w,head):
//   chunk = (n>>4)*2 + (hd>>4); elem = (((n>>2)&3)*16 + (hd&15))*4 + (n&3)
// K stored in K=32 QK A-fragment order per (w,head):
//   off = (n>>4)*512 + ((hd>>3)*16 + (n&15))*8 + (hd&7)
__global__ __launch_bounds__(256) void gemm_qkv(
    const ushort* __restrict__ A,   // [32768][256] bf16
    const ushort* __restrict__ Bw,  // [768][256] bf16
    const float* __restrict__ bq,
    ushort* __restrict__ Q, ushort* __restrict__ K, ushort* __restrict__ Vf) {
    __shared__ short As[128 * 64];
    __shared__ short Bs[128 * 64];
    const int t = threadIdx.x;
    const int wv = t >> 6, lane = t & 63, quad = lane >> 4, col = lane & 15;
    const int m0 = blockIdx.y * 128, n0 = blockIdx.x * 128;
    const int wm = (wv & 1) * 64, wn = (wv >> 1) * 64;

    floatx4 zf = {0.f, 0.f, 0.f, 0.f};
    floatx4 acc[4][4];
#pragma unroll
    for (int i = 0; i < 4; ++i)
#pragma unroll
        for (int j = 0; j < 4; ++j) acc[i][j] = zf;

    for (int kk = 0; kk < 256; kk += 64) {
        __syncthreads();
#pragma unroll
        for (int i = 0; i < 4; ++i) {
            int s = i * 256 + t;
            int row = s >> 3, qs = s & 7;
            int qg = qs ^ (row & 7);
            gl_lds16(A + (size_t)(m0 + row) * 256 + kk + qg * 8,
                     As + (i * 256 + wv * 64) * 8);
        }
#pragma unroll
        for (int i = 0; i < 4; ++i) {
            int s = i * 256 + t;
            int row = s >> 3, qs = s & 7;
            int qg = qs ^ (row & 7);
            gl_lds16(Bw + (size_t)(n0 + row) * 256 + kk + qg * 8,
                     Bs + (i * 256 + wv * 64) * 8);
        }
        __syncthreads();
#pragma unroll
        for (int h = 0; h < 2; ++h) {
            short8 af[4], bf[4];
#pragma unroll
            for (int mi = 0; mi < 4; ++mi) {
                int row = wm + mi * 16 + col;
                af[mi] = *(const short8*)(As + (row * 8 + ((h * 4 + quad) ^ (row & 7))) * 8);
            }
#pragma unroll
            for (int ni = 0; ni < 4; ++ni) {
                int row = wn + ni * 16 + col;
                bf[ni] = *(const short8*)(Bs + (row * 8 + ((h * 4 + quad) ^ (row & 7))) * 8);
            }
#pragma unroll
            for (int mi = 0; mi < 4; ++mi)
#pragma unroll
                for (int ni = 0; ni < 4; ++ni)
                    acc[mi][ni] = __builtin_amdgcn_mfma_f32_16x16x32_bf16(af[mi], bf[ni], acc[mi][ni], 0, 0, 0);
        }
    }

#pragma unroll
    for (int ni = 0; ni < 4; ++ni) {
        int j = n0 + wn + ni * 16 + col;
        int three = j >> 8, head = (j >> 5) & 7, hd = j & 31;
        float bias = bq[j] * ((j < 256) ? (QSCALE * LOG2E) : 1.0f);
        if (three == 2) {
            int h = hd >> 4, colv = hd & 15;
#pragma unroll
            for (int mi = 0; mi < 4; ++mi) {
                int mb = m0 + wm + mi * 16 + quad * 4;   // n&3 = r, contiguous
                int w = mb >> 9, n = mb & 511;
                size_t off = ((size_t)((w * 8 + head) * 64 + (n >> 4) * 2 + h) << 8)
                           + ((((n >> 2) & 3) * 16 + colv) << 2);
                uint2v pv;
                pv[0] = pk2bf(acc[mi][ni][0] + bias, acc[mi][ni][1] + bias);
                pv[1] = pk2bf(acc[mi][ni][2] + bias, acc[mi][ni][3] + bias);
                *(uint2v*)(Vf + off) = pv;
            }
        } else if (three == 1) {
            // K in QK A-fragment order (lane (hd>>3)*16+(n&15) reads 16B at frag+lane*16)
#pragma unroll
            for (int mi = 0; mi < 4; ++mi) {
#pragma unroll
                for (int r = 0; r < 4; ++r) {
                    int m = m0 + wm + mi * 16 + quad * 4 + r;
                    int w = m >> 9, n = m & 511;
                    size_t off = ((size_t)(w * 8 + head) << 14) + ((size_t)(n >> 4) << 9)
                               + (((hd >> 3) * 16 + (n & 15)) << 3) + (hd & 7);
                    K[off] = f2bf(acc[mi][ni][r] + bias);
                }
            }
        } else {
#pragma unroll
            for (int mi = 0; mi < 4; ++mi) {
#pragma unroll
                for (int r = 0; r < 4; ++r) {
                    int m = m0 + wm + mi * 16 + quad * 4 + r;
                    int w = m >> 9, n = m & 511;
                    Q[((size_t)(w * 8 + head) * 512 + n) * 32 + hd] = f2bf(acc[mi][ni][r] + bias);
                }
            }
        }
    }
}

// ---------------- MFMA GEMM: out = Y @ Wpb^T + bp, scatter w/ reverse shift ----------
__global__ __launch_bounds__(256) void gemm_proj(
    const ushort* __restrict__ A,   // Y [32768][256] bf16
    const ushort* __restrict__ Bw,  // [256][256] bf16
    const float* __restrict__ bp,
    float* __restrict__ out) {
    __shared__ short As[128 * 64];
    __shared__ short Bs[128 * 64];
    const int t = threadIdx.x;
    const int wv = t >> 6, lane = t & 63, quad = lane >> 4, col = lane & 15;
    const int m0 = blockIdx.y * 128, n0 = blockIdx.x * 128;
    const int wm = (wv & 1) * 64, wn = (wv >> 1) * 64;

    floatx4 zf = {0.f, 0.f, 0.f, 0.f};
    floatx4 acc[4][4];
#pragma unroll
    for (int i = 0; i < 4; ++i)
#pragma unroll
        for (int j = 0; j < 4; ++j) acc[i][j] = zf;

    for (int kk = 0; kk < 256; kk += 64) {
        __syncthreads();
#pragma unroll
        for (int i = 0; i < 4; ++i) {
            int s = i * 256 + t;
            int row = s >> 3, qs = s & 7;
            int qg = qs ^ (row & 7);
            gl_lds16(A + (size_t)(m0 + row) * 256 + kk + qg * 8,
                     As + (i * 256 + wv * 64) * 8);
        }
#pragma unroll
        for (int i = 0; i < 4; ++i) {
            int s = i * 256 + t;
            int row = s >> 3, qs = s & 7;
            int qg = qs ^ (row & 7);
            gl_lds16(Bw + (size_t)(n0 + row) * 256 + kk + qg * 8,
                     Bs + (i * 256 + wv * 64) * 8);
        }
        __syncthreads();
#pragma unroll
        for (int h = 0; h < 2; ++h) {
            short8 af[4], bf[4];
#pragma unroll
            for (int mi = 0; mi < 4; ++mi) {
                int row = wm + mi * 16 + col;
                af[mi] = *(const short8*)(As + (row * 8 + ((h * 4 + quad) ^ (row & 7))) * 8);
            }
#pragma unroll
            for (int ni = 0; ni < 4; ++ni) {
                int row = wn + ni * 16 + col;
                bf[ni] = *(const short8*)(Bs + (row * 8 + ((h * 4 + quad) ^ (row & 7))) * 8);
            }
#pragma unroll
            for (int mi = 0; mi < 4; ++mi)
#pragma unroll
                for (int ni = 0; ni < 4; ++ni)
                    acc[mi][ni] = __builtin_amdgcn_mfma_f32_16x16x32_bf16(af[mi], bf[ni], acc[mi][ni], 0, 0, 0);
        }
    }

#pragma unroll
    for (int ni = 0; ni < 4; ++ni) {
        int j = n0 + wn + ni * 16 + col;
        float bias = bp[j];
#pragma unroll
        for (int mi = 0; mi < 4; ++mi) {
#pragma unroll
            for (int r = 0; r < 4; ++r) {
                int m = m0 + wm + mi * 16 + quad * 4 + r;
                out[spatial_off(m) + j] = acc[mi][ni][r] + bias;
            }
        }
    }
}

// ---------------- MFMA windowed attention v10 ----------------
// v9 body verbatim; grid 512 -> 1024 (two q-halves per (w,head)) so the 3rd
// block slot the 46.6KB LDS permits is actually fillable (v9 lesson: LDS said
// 3 blocks/CU, grid said 2 -> occupancy flat). 8 waves/block, wave owns 2
// q-tiles. Staging volume per (w,head) unchanged vs v9 (2 blocks x 4 stages).
__global__ __launch_bounds__(512, 2) void attn_kernel(
    const ushort* __restrict__ Q, const ushort* __restrict__ K,
    const ushort* __restrict__ Vf, const uint* __restrict__ Up,
    ushort* __restrict__ Y) {
    __shared__ short Kl[256 * 32];       // 16KB, current chunk, QK A-fragment order
    __shared__ short Vs[32 * 256];       // 16KB, current chunk, PV A-fragment order
    __shared__ uint  Ul[3375];           // 13.5KB per-head rel-pos pair table

    const int t = threadIdx.x;
    const int bid = blockIdx.x;
    const int w = bid >> 4, head = (bid >> 1) & 7, half = bid & 1;
    const int wh = w >> 4, ww = (w >> 2) & 3, wd = w & 3;
    const int wv = t >> 6, lane = t & 63, quad = lane >> 4, col = lane & 15;

    const ushort* Kg = K + (size_t)(w * 8 + head) * 16384;
    const ushort* Vg = Vf + (size_t)(w * 8 + head) * 16384;
    const ushort* Qg = Q + (size_t)(w * 8 + head) * 16384;

    // ---- stage this head's pair table (barrier below covers visibility) ----
    const uint* Uph = Up + head * 3375;
    for (int i = t; i < 3375; i += 512) Ul[i] = Uph[i];

    const bool boundary = (wh == 3) | (ww == 3) | (wd == 3);
    floatx4 zf = {0.f, 0.f, 0.f, 0.f};

    for (int qs = 0; qs < 2; ++qs) {
        const int qt = half * 16 + wv * 2 + qs;
        const short8 qf = *(const short8*)(Qg + (size_t)(qt * 16 + col) * 32 + quad * 8);

        const int qrow = qt * 16 + col;
        const int qh = qrow >> 6, qw = (qrow >> 3) & 7, qd = qrow & 7;
        const int Base0 = ((qh + 7) * 15 + (qw + 7 - (quad >> 1))) * 15
                        + (qd - ((quad & 1) << 2) + 7);
        const int cq = ((wh == 3) ? (1 + ((qrow >> 8) & 1)) * 16 : 0)
                     + ((ww == 3) ? (1 + ((qrow >> 5) & 1)) * 4 : 0)
                     + ((wd == 3) ? (1 + ((qrow >> 2) & 1)) : 0);

        float rs = 0.f;
        floatx4 o0 = zf, o1 = zf;

        // ---- keys in 2 chunks of 256: stage chunk, then produce+consume ----
        for (int c = 0; c < 2; ++c) {   // block-uniform; rolled keeps liveness low
            __syncthreads();            // all waves done with previous chunk
#pragma unroll
            for (int i = 0; i < 2; ++i) {
                gl_lds16(Kg + (size_t)(c * 8192 + (i * 512 + t) * 8), Kl + (i * 512 + wv * 64) * 8);
                gl_lds16(Vg + (size_t)(c * 8192 + (i * 512 + t) * 8), Vs + (i * 512 + wv * 64) * 8);
            }
            __syncthreads();            // chunk staged (compiler drains vmcnt)

            const int BaseC = Base0 - c * 900;
            const int ckh = (wh == 3) ? ((1 + c) * 16) : 0;

            floatx4 acc[16];
            // produce: S^T tiles with bias (and mask) preloaded into the C operand
#pragma unroll
            for (int tt = 0; tt < 16; ++tt) {
                const int Kt2 = ((tt >> 2) * 15 + (tt & 3) * 2) * 15;
                uint p0 = Ul[BaseC - Kt2];
                uint p1 = Ul[BaseC - Kt2 - 2];
                floatx4 cf;
                cf[0] = __uint_as_float(p0 << 16);
                cf[1] = __uint_as_float(p0 & 0xffff0000u);
                cf[2] = __uint_as_float(p1 << 16);
                cf[3] = __uint_as_float(p1 & 0xffff0000u);
                if (boundary) {
                    int ck = ckh
                           + ((ww == 3) ? (1 + ((tt >> 1) & 1)) * 4 : 0)
                           + ((wd == 3) ? (1 + (quad & 1)) : 0);
                    float madd = (cq == ck) ? 0.f : -144.269504f;  // -100*log2e
                    cf[0] += madd; cf[1] += madd; cf[2] += madd; cf[3] += madd;
                }
                short8 kf = *(const short8*)(Kl + tt * 512 + lane * 8);
                acc[tt] = __builtin_amdgcn_mfma_f32_16x16x32_bf16(kf, qf, cf, 0, 0, 0);
            }

            // consume: raw v_exp (scores already in log2 domain), pack, PV
#pragma unroll
            for (int tt = 0; tt < 16; ++tt) {
                float e0 = __builtin_amdgcn_exp2f(acc[tt][0]);
                float e1 = __builtin_amdgcn_exp2f(acc[tt][1]);
                float e2 = __builtin_amdgcn_exp2f(acc[tt][2]);
                float e3 = __builtin_amdgcn_exp2f(acc[tt][3]);
                rs += (e0 + e1) + (e2 + e3);
                uint2v pp;
                pp[0] = pk2bf(e0, e1);
                pp[1] = pk2bf(e2, e3);
                s4v pf = __builtin_bit_cast(s4v, pp);
                s4v v0 = *(const s4v*)(Vs + ((tt * 2 + 0) << 8) + lane * 4);
                s4v v1 = *(const s4v*)(Vs + ((tt * 2 + 1) << 8) + lane * 4);
                o0 = __builtin_amdgcn_mfma_f32_16x16x16bf16_1k(v0, pf, o0, 0, 0, 0);
                o1 = __builtin_amdgcn_mfma_f32_16x16x16bf16_1k(v1, pf, o1, 0, 0, 0);
            }
        }

        rs += __shfl_xor(rs, 16);
        rs += __shfl_xor(rs, 32);
        const float inv = __builtin_amdgcn_rcpf(rs);

        // ---- epilogue: O^T row=hd(quad*4+r), col=q(lane&15); two packed 8B stores ----
        int token = w * 512 + qt * 16 + col;
        ushort* Yb = Y + (size_t)token * 256 + head * 32 + quad * 4;
        uint2v y0, y1;
        y0[0] = pk2bf(o0[0] * inv, o0[1] * inv);
        y0[1] = pk2bf(o0[2] * inv, o0[3] * inv);
        y1[0] = pk2bf(o1[0] * inv, o1[1] * inv);
        y1[1] = pk2bf(o1[2] * inv, o1[3] * inv);
        *(uint2v*)(Yb) = y0;
        *(uint2v*)(Yb + 16) = y1;
    }
}

extern "C" void kernel_launch(void* const* d_in, const int* in_sizes, int n_in,
                              void* d_out, int out_size, void* d_ws, size_t ws_size,
                              hipStream_t stream) {
    const float* x      = (const float*)d_in[0];
    const float* qkv_w  = (const float*)d_in[1];
    const float* qkv_b  = (const float*)d_in[2];
    const float* proj_w = (const float*)d_in[3];
    const float* proj_b = (const float*)d_in[4];
    const float* rpb    = (const float*)d_in[5];
    float* out = (float*)d_out;

    // ws layout (ushorts): Xw 8.39M | Q 8.39M | K 8.39M | Vf 8.39M | Y 8.39M | Up 54K | Wqb | Wpb
    ushort* Xw  = (ushort*)d_ws;
    ushort* Q   = Xw + 8388608;
    ushort* K   = Q + 8388608;
    ushort* Vf  = K + 8388608;
    ushort* Y   = Vf + 8388608;
    uint*   Up  = (uint*)(Y + 8388608);
    ushort* Wqb = (ushort*)(Up + 27008);
    ushort* Wpb = Wqb + 196608;

    xconv<<<dim3(4096), dim3(256), 0, stream>>>(x, Xw);
    wconv<<<dim3(1024), dim3(256), 0, stream>>>(qkv_w, proj_w, Wqb, Wpb);
    pair_prep<<<dim3(106), dim3(256), 0, stream>>>(rpb, Up);
    gemm_qkv<<<dim3(6, 256), dim3(256), 0, stream>>>(Xw, Wqb, qkv_b, Q, K, Vf);
    attn_kernel<<<dim3(1024), dim3(512), 0, stream>>>(Q, K, Vf, Up, Y);
    gemm_proj<<<dim3(2, 256), dim3(256), 0, stream>>>(Y, Wpb, proj_b, out);
}

// Round 10
// 172.006 us; speedup vs baseline: 1.0379x; 1.0379x over previous
//
#include <hip/hip_runtime.h>

typedef __attribute__((ext_vector_type(8))) short short8;
typedef __attribute__((ext_vector_type(4))) short s4v;
typedef __attribute__((ext_vector_type(2))) uint uint2v;
typedef __attribute__((ext_vector_type(4))) uint uint4v;
typedef __attribute__((ext_vector_type(4))) float floatx4;

#define CCH   256
#define QSCALE 0.17677669529663687f  // 32^-0.5
#define LOG2E  1.4426950408889634f

__device__ __forceinline__ unsigned short f2bf(float f) {
    unsigned u = __float_as_uint(f);
    u = u + 0x7fffu + ((u >> 16) & 1u);
    return (unsigned short)(u >> 16);
}

// pack two fp32 -> bf16x2 with round-half-up: (u+0x8000)>>16, fused via v_perm
__device__ __forceinline__ uint pk2bf(float a, float b) {
    uint ua = __float_as_uint(a) + 0x8000u;
    uint ub = __float_as_uint(b) + 0x8000u;
    return __builtin_amdgcn_perm(ub, ua, 0x07060302u);
}

__device__ __forceinline__ void gl_lds16(const void* g, void* l) {
    __builtin_amdgcn_global_load_lds((const __attribute__((address_space(1))) void*)g,
                                     (__attribute__((address_space(3))) void*)l, 16, 0, 0);
}

// token (w*512+n) -> flat spatial offset (*CCH) in x/out with +4 cyclic shift
__device__ __forceinline__ int spatial_off(int token) {
    int w = token >> 9, n = token & 511;
    int wh = w >> 4, ww = (w >> 2) & 3, wd = w & 3;
    int h1 = n >> 6, w1 = (n >> 3) & 7, d1 = n & 7;
    int gh = (wh * 8 + h1 + 4) & 31;
    int gw = (ww * 8 + w1 + 4) & 31;
    int gd = (wd * 8 + d1 + 4) & 31;
    return ((gh * 32 + gw) * 32 + gd) * CCH;
}

// ---------------- fused preprocessing: xconv | wconv | pair_prep ----------------
// blocks [0,4096): x (fp32, spatial) -> Xw (bf16, window-token order)
// blocks [4096,5120): weights fp32 -> bf16 (QSCALE*LOG2E folded into Wq rows 0-255)
// blocks [5120,5226): rel-pos pair table (pre-scaled by LOG2E)
__global__ __launch_bounds__(256) void prep(const float* __restrict__ x,
                                            const float* __restrict__ Wq,
                                            const float* __restrict__ Wp,
                                            const float* __restrict__ rpb,
                                            ushort* __restrict__ Xw,
                                            ushort* __restrict__ Wqb,
                                            ushort* __restrict__ Wpb,
                                            uint* __restrict__ Up) {
    int b = blockIdx.x;
    if (b < 4096) {
        int tid = b * 256 + threadIdx.x;   // 1048576
        int token = tid >> 5, c8 = (tid & 31) * 8;
        const float* src = x + spatial_off(token) + c8;
        float4 a = *(const float4*)src;
        float4 bb = *(const float4*)(src + 4);
        uint2v lo, hi;
        lo[0] = pk2bf(a.x, a.y);
        lo[1] = pk2bf(a.z, a.w);
        hi[0] = pk2bf(bb.x, bb.y);
        hi[1] = pk2bf(bb.z, bb.w);
        uint2v* dst = (uint2v*)(Xw + (size_t)token * 256 + c8);
        dst[0] = lo;
        dst[1] = hi;
    } else if (b < 5120) {
        int tid = (b - 4096) * 256 + threadIdx.x;   // 262144
        if (tid < 196608) {
            float s = (tid < 65536) ? (QSCALE * LOG2E) : 1.0f;
            Wqb[tid] = f2bf(Wq[tid] * s);
        } else {
            int i = tid - 196608;
            Wpb[i] = f2bf(Wp[i]);
        }
    } else {
        int tid = (b - 5120) * 256 + threadIdx.x;   // 27000
        if (tid >= 27000) return;
        int head = tid / 3375, idx = tid - head * 3375;
        uint lo = f2bf(rpb[idx * 8 + head] * LOG2E);
        uint hi = f2bf(rpb[(idx > 0 ? idx - 1 : 0) * 8 + head] * LOG2E);
        Up[tid] = lo | (hi << 16);
    }
}

// ---------------- MFMA GEMM: C[32768 x 768] = Xw @ Wqb^T -> Q/K/Vf ----------------
// V stored in K=16 MFMA A-fragment order per (w,head):
//   chunk = (n>>4)*2 + (hd>>4); elem = (((n>>2)&3)*16 + (hd&15))*4 + (n&3)
// K stored in K=32 QK A-fragment order per (w,head):
//   off = (n>>4)*512 + ((hd>>3)*16 + (n&15))*8 + (hd&7)
// Q/K epilogue: LDS-bounce transpose (tile -> Sh stride 136 -> 16B packed stores)
// replacing 64 scalar 2B scattered stores/thread with 8 coalesced dwordx4.
__global__ __launch_bounds__(256) void gemm_qkv(
    const ushort* __restrict__ A,   // [32768][256] bf16
    const ushort* __restrict__ Bw,  // [768][256] bf16
    const float* __restrict__ bq,
    ushort* __restrict__ Q, ushort* __restrict__ K, ushort* __restrict__ Vf) {
    __shared__ short Sh[17408];     // main loop: As=Sh[0:8192], Bs=Sh[8192:16384]
                                    // epilogue:  128x136 bf16 tile (rows 16B-aligned)
    short* As = Sh;
    short* Bs = Sh + 8192;
    const int t = threadIdx.x;
    const int wv = t >> 6, lane = t & 63, quad = lane >> 4, col = lane & 15;
    const int m0 = blockIdx.y * 128, n0 = blockIdx.x * 128;
    const int wm = (wv & 1) * 64, wn = (wv >> 1) * 64;

    floatx4 zf = {0.f, 0.f, 0.f, 0.f};
    floatx4 acc[4][4];
#pragma unroll
    for (int i = 0; i < 4; ++i)
#pragma unroll
        for (int j = 0; j < 4; ++j) acc[i][j] = zf;

    for (int kk = 0; kk < 256; kk += 64) {
        __syncthreads();
#pragma unroll
        for (int i = 0; i < 4; ++i) {
            int s = i * 256 + t;
            int row = s >> 3, qs = s & 7;
            int qg = qs ^ (row & 7);
            gl_lds16(A + (size_t)(m0 + row) * 256 + kk + qg * 8,
                     As + (i * 256 + wv * 64) * 8);
        }
#pragma unroll
        for (int i = 0; i < 4; ++i) {
            int s = i * 256 + t;
            int row = s >> 3, qs = s & 7;
            int qg = qs ^ (row & 7);
            gl_lds16(Bw + (size_t)(n0 + row) * 256 + kk + qg * 8,
                     Bs + (i * 256 + wv * 64) * 8);
        }
        __syncthreads();
#pragma unroll
        for (int h = 0; h < 2; ++h) {
            short8 af[4], bf[4];
#pragma unroll
            for (int mi = 0; mi < 4; ++mi) {
                int row = wm + mi * 16 + col;
                af[mi] = *(const short8*)(As + (row * 8 + ((h * 4 + quad) ^ (row & 7))) * 8);
            }
#pragma unroll
            for (int ni = 0; ni < 4; ++ni) {
                int row = wn + ni * 16 + col;
                bf[ni] = *(const short8*)(Bs + (row * 8 + ((h * 4 + quad) ^ (row & 7))) * 8);
            }
#pragma unroll
            for (int mi = 0; mi < 4; ++mi)
#pragma unroll
                for (int ni = 0; ni < 4; ++ni)
                    acc[mi][ni] = __builtin_amdgcn_mfma_f32_16x16x32_bf16(af[mi], bf[ni], acc[mi][ni], 0, 0, 0);
        }
    }

    const int bx = blockIdx.x;   // 0,1: Q   2,3: K   4,5: V  (block-uniform)
    if (bx >= 4) {
        // ---- V: direct packed stores (fragment order already n-contiguous) ----
#pragma unroll
        for (int ni = 0; ni < 4; ++ni) {
            int j = n0 + wn + ni * 16 + col;
            int head = (j >> 5) & 7, hd = j & 31;
            float bias = bq[j];
            int h = hd >> 4, colv = hd & 15;
#pragma unroll
            for (int mi = 0; mi < 4; ++mi) {
                int mb = m0 + wm + mi * 16 + quad * 4;   // n&3 = r, contiguous
                int w = mb >> 9, n = mb & 511;
                size_t off = ((size_t)((w * 8 + head) * 64 + (n >> 4) * 2 + h) << 8)
                           + ((((n >> 2) & 3) * 16 + colv) << 2);
                uint2v pv;
                pv[0] = pk2bf(acc[mi][ni][0] + bias, acc[mi][ni][1] + bias);
                pv[1] = pk2bf(acc[mi][ni][2] + bias, acc[mi][ni][3] + bias);
                *(uint2v*)(Vf + off) = pv;
            }
        }
    } else {
        // ---- Q/K: LDS-bounce. Dump tile to Sh[row][jloc] (stride 136), then
        //      each thread writes 8 coalesced 16B chunks. ----
        __syncthreads();   // all waves done reading As/Bs
#pragma unroll
        for (int ni = 0; ni < 4; ++ni) {
            int j = n0 + wn + ni * 16 + col;
            int jloc = wn + ni * 16 + col;
            float bias = bq[j] * ((j < 256) ? (QSCALE * LOG2E) : 1.0f);
#pragma unroll
            for (int mi = 0; mi < 4; ++mi) {
                int rowb = wm + mi * 16 + quad * 4;
#pragma unroll
                for (int r = 0; r < 4; ++r)
                    Sh[(rowb + r) * 136 + jloc] = (short)f2bf(acc[mi][ni][r] + bias);
            }
        }
        __syncthreads();
        ushort* dst = (bx < 2) ? Q : K;
#pragma unroll
        for (int k8 = 0; k8 < 8; ++k8) {
            int chunk = k8 * 256 + t;        // 0..2047
            int row = chunk >> 4;            // 0..127
            int jl = (chunk & 15) * 8;       // 0..120
            int j = n0 + jl;
            int m = m0 + row;
            int w = m >> 9, n = m & 511;
            int head = (j >> 5) & 7, hd = j & 31;
            uint4v vv = *(const uint4v*)(Sh + row * 136 + jl);
            size_t off;
            if (bx < 2) {
                off = ((size_t)(w * 8 + head) * 512 + n) * 32 + hd;          // row-major
            } else {
                off = ((size_t)(w * 8 + head) << 14) + ((size_t)(n >> 4) << 9)
                    + (((hd >> 3) * 16 + (n & 15)) << 3);                    // frag order
            }
            *(uint4v*)(dst + off) = vv;
        }
    }
}

// ---------------- MFMA GEMM: out = Y @ Wpb^T + bp, scatter w/ reverse shift ----------
__global__ __launch_bounds__(256) void gemm_proj(
    const ushort* __restrict__ A,   // Y [32768][256] bf16
    const ushort* __restrict__ Bw,  // [256][256] bf16
    const float* __restrict__ bp,
    float* __restrict__ out) {
    __shared__ short As[128 * 64];
    __shared__ short Bs[128 * 64];
    const int t = threadIdx.x;
    const int wv = t >> 6, lane = t & 63, quad = lane >> 4, col = lane & 15;
    const int m0 = blockIdx.y * 128, n0 = blockIdx.x * 128;
    const int wm = (wv & 1) * 64, wn = (wv >> 1) * 64;

    floatx4 zf = {0.f, 0.f, 0.f, 0.f};
    floatx4 acc[4][4];
#pragma unroll
    for (int i = 0; i < 4; ++i)
#pragma unroll
        for (int j = 0; j < 4; ++j) acc[i][j] = zf;

    for (int kk = 0; kk < 256; kk += 64) {
        __syncthreads();
#pragma unroll
        for (int i = 0; i < 4; ++i) {
            int s = i * 256 + t;
            int row = s >> 3, qs = s & 7;
            int qg = qs ^ (row & 7);
            gl_lds16(A + (size_t)(m0 + row) * 256 + kk + qg * 8,
                     As + (i * 256 + wv * 64) * 8);
        }
#pragma unroll
        for (int i = 0; i < 4; ++i) {
            int s = i * 256 + t;
            int row = s >> 3, qs = s & 7;
            int qg = qs ^ (row & 7);
            gl_lds16(Bw + (size_t)(n0 + row) * 256 + kk + qg * 8,
                     Bs + (i * 256 + wv * 64) * 8);
        }
        __syncthreads();
#pragma unroll
        for (int h = 0; h < 2; ++h) {
            short8 af[4], bf[4];
#pragma unroll
            for (int mi = 0; mi < 4; ++mi) {
                int row = wm + mi * 16 + col;
                af[mi] = *(const short8*)(As + (row * 8 + ((h * 4 + quad) ^ (row & 7))) * 8);
            }
#pragma unroll
            for (int ni = 0; ni < 4; ++ni) {
                int row = wn + ni * 16 + col;
                bf[ni] = *(const short8*)(Bs + (row * 8 + ((h * 4 + quad) ^ (row & 7))) * 8);
            }
#pragma unroll
            for (int mi = 0; mi < 4; ++mi)
#pragma unroll
                for (int ni = 0; ni < 4; ++ni)
                    acc[mi][ni] = __builtin_amdgcn_mfma_f32_16x16x32_bf16(af[mi], bf[ni], acc[mi][ni], 0, 0, 0);
        }
    }

#pragma unroll
    for (int ni = 0; ni < 4; ++ni) {
        int j = n0 + wn + ni * 16 + col;
        float bias = bp[j];
#pragma unroll
        for (int mi = 0; mi < 4; ++mi) {
#pragma unroll
            for (int r = 0; r < 4; ++r) {
                int m = m0 + wm + mi * 16 + quad * 4 + r;
                out[spatial_off(m) + j] = acc[mi][ni][r] + bias;
            }
        }
    }
}

// ---------------- MFMA windowed attention (v8, best measured: 47.5us) ----------------
// 512 threads (8 waves), grid 512, one-shot K/V staging (77.5KB LDS, 2 blocks/CU),
// K/V pre-permuted to fragment order in global, raw v_exp_f32, (512,2) bounds.
// Occupancy experiments (46.6KB LDS chunked, grid 1024) were nulls: 8-wave blocks
// cap at 2/CU on this part regardless of LDS; chunking costs +33MB FETCH + barriers.
__global__ __launch_bounds__(512, 2) void attn_kernel(
    const ushort* __restrict__ Q, const ushort* __restrict__ K,
    const ushort* __restrict__ Vf, const uint* __restrict__ Up,
    ushort* __restrict__ Y) {
    __shared__ short Kl[512 * 32];       // QK A-fragment order (pre-permuted in global)
    __shared__ short Vs[64 * 256];       // PV A-fragment order (pre-permuted in global)
    __shared__ uint  Ul[3375];           // per-head rel-pos pair table (log2-scaled)

    const int t = threadIdx.x;
    const int bid = blockIdx.x;
    const int w = bid >> 3, head = bid & 7;
    const int wh = w >> 4, ww = (w >> 2) & 3, wd = w & 3;
    const int wv = t >> 6, lane = t & 63, quad = lane >> 4, col = lane & 15;

    const ushort* Kg = K + (size_t)(w * 8 + head) * 512 * 32;
    const ushort* Vg = Vf + (size_t)(w * 8 + head) * 512 * 32;
    const ushort* Qg = Q + (size_t)(w * 8 + head) * 512 * 32;

    // ---- stage K and V once (async direct-to-LDS, linear; 512 threads x 4 iters) ----
#pragma unroll
    for (int i = 0; i < 4; ++i) {
        gl_lds16(Kg + (size_t)(i * 512 + t) * 8, Kl + (i * 512 + wv * 64) * 8);
        gl_lds16(Vg + (size_t)(i * 512 + t) * 8, Vs + (i * 512 + wv * 64) * 8);
    }
    // ---- stage this head's pair table ----
    const uint* Uph = Up + head * 3375;
    for (int i = t; i < 3375; i += 512) Ul[i] = Uph[i];
    __syncthreads();

    const bool boundary = (wh == 3) | (ww == 3) | (wd == 3);
    floatx4 zf = {0.f, 0.f, 0.f, 0.f};

    for (int qs = 0; qs < 4; ++qs) {
        const int qt = wv * 4 + qs;
        const short8 qf = *(const short8*)(Qg + (size_t)(qt * 16 + col) * 32 + quad * 8);

        const int qrow = qt * 16 + col;
        const int qh = qrow >> 6, qw = (qrow >> 3) & 7, qd = qrow & 7;
        const int Base0 = ((qh + 7) * 15 + (qw + 7 - (quad >> 1))) * 15
                        + (qd - ((quad & 1) << 2) + 7);
        const int cq = ((wh == 3) ? (1 + ((qrow >> 8) & 1)) * 16 : 0)
                     + ((ww == 3) ? (1 + ((qrow >> 5) & 1)) * 4 : 0)
                     + ((wd == 3) ? (1 + ((qrow >> 2) & 1)) : 0);

        float rs = 0.f;
        floatx4 o0 = zf, o1 = zf;

        // ---- keys in 2 chunks of 256: acc[16] produced & consumed per chunk ----
        for (int c = 0; c < 2; ++c) {   // rolled: keeps register liveness low
            const short* KlC = Kl + c * 8192;
            const short* VsC = Vs + c * 8192;
            const int BaseC = Base0 - c * 900;
            const int ckh = (wh == 3) ? ((1 + c) * 16) : 0;

            floatx4 acc[16];
            // produce: S^T tiles with bias (and mask) preloaded into the C operand
#pragma unroll
            for (int tt = 0; tt < 16; ++tt) {
                const int Kt2 = ((tt >> 2) * 15 + (tt & 3) * 2) * 15;
                uint p0 = Ul[BaseC - Kt2];
                uint p1 = Ul[BaseC - Kt2 - 2];
                floatx4 cf;
                cf[0] = __uint_as_float(p0 << 16);
                cf[1] = __uint_as_float(p0 & 0xffff0000u);
                cf[2] = __uint_as_float(p1 << 16);
                cf[3] = __uint_as_float(p1 & 0xffff0000u);
                if (boundary) {
                    int ck = ckh
                           + ((ww == 3) ? (1 + ((tt >> 1) & 1)) * 4 : 0)
                           + ((wd == 3) ? (1 + (quad & 1)) : 0);
                    float madd = (cq == ck) ? 0.f : -144.269504f;  // -100*log2e
                    cf[0] += madd; cf[1] += madd; cf[2] += madd; cf[3] += madd;
                }
                short8 kf = *(const short8*)(KlC + tt * 512 + lane * 8);
                acc[tt] = __builtin_amdgcn_mfma_f32_16x16x32_bf16(kf, qf, cf, 0, 0, 0);
            }

            // consume: raw v_exp (scores already in log2 domain), pack, PV
#pragma unroll
            for (int tt = 0; tt < 16; ++tt) {
                float e0 = __builtin_amdgcn_exp2f(acc[tt][0]);
                float e1 = __builtin_amdgcn_exp2f(acc[tt][1]);
                float e2 = __builtin_amdgcn_exp2f(acc[tt][2]);
                float e3 = __builtin_amdgcn_exp2f(acc[tt][3]);
                rs += (e0 + e1) + (e2 + e3);
                uint2v pp;
                pp[0] = pk2bf(e0, e1);
                pp[1] = pk2bf(e2, e3);
                s4v pf = __builtin_bit_cast(s4v, pp);
                s4v v0 = *(const s4v*)(VsC + ((tt * 2 + 0) << 8) + lane * 4);
                s4v v1 = *(const s4v*)(VsC + ((tt * 2 + 1) << 8) + lane * 4);
                o0 = __builtin_amdgcn_mfma_f32_16x16x16bf16_1k(v0, pf, o0, 0, 0, 0);
                o1 = __builtin_amdgcn_mfma_f32_16x16x16bf16_1k(v1, pf, o1, 0, 0, 0);
            }
        }

        rs += __shfl_xor(rs, 16);
        rs += __shfl_xor(rs, 32);
        const float inv = __builtin_amdgcn_rcpf(rs);

        // ---- epilogue: O^T row=hd(quad*4+r), col=q(lane&15); two packed 8B stores ----
        int token = w * 512 + qt * 16 + col;
        ushort* Yb = Y + (size_t)token * 256 + head * 32 + quad * 4;
        uint2v y0, y1;
        y0[0] = pk2bf(o0[0] * inv, o0[1] * inv);
        y0[1] = pk2bf(o0[2] * inv, o0[3] * inv);
        y1[0] = pk2bf(o1[0] * inv, o1[1] * inv);
        y1[1] = pk2bf(o1[2] * inv, o1[3] * inv);
        *(uint2v*)(Yb) = y0;
        *(uint2v*)(Yb + 16) = y1;
    }
}

extern "C" void kernel_launch(void* const* d_in, const int* in_sizes, int n_in,
                              void* d_out, int out_size, void* d_ws, size_t ws_size,
                              hipStream_t stream) {
    const float* x      = (const float*)d_in[0];
    const float* qkv_w  = (const float*)d_in[1];
    const float* qkv_b  = (const float*)d_in[2];
    const float* proj_w = (const float*)d_in[3];
    const float* proj_b = (const float*)d_in[4];
    const float* rpb    = (const float*)d_in[5];
    float* out = (float*)d_out;

    // ws layout (ushorts): Xw 8.39M | Q 8.39M | K 8.39M | Vf 8.39M | Y 8.39M | Up 54K | Wqb | Wpb
    ushort* Xw  = (ushort*)d_ws;
    ushort* Q   = Xw + 8388608;
    ushort* K   = Q + 8388608;
    ushort* Vf  = K + 8388608;
    ushort* Y   = Vf + 8388608;
    uint*   Up  = (uint*)(Y + 8388608);
    ushort* Wqb = (ushort*)(Up + 27008);
    ushort* Wpb = Wqb + 196608;

    prep<<<dim3(5226), dim3(256), 0, stream>>>(x, qkv_w, proj_w, rpb, Xw, Wqb, Wpb, Up);
    gemm_qkv<<<dim3(6, 256), dim3(256), 0, stream>>>(Xw, Wqb, qkv_b, Q, K, Vf);
    attn_kernel<<<dim3(512), dim3(512), 0, stream>>>(Q, K, Vf, Up, Y);
    gemm_proj<<<dim3(2, 256), dim3(256), 0, stream>>>(Y, Wpb, proj_b, out);
}

// Round 11
// 171.422 us; speedup vs baseline: 1.0414x; 1.0034x over previous
//
#include <hip/hip_runtime.h>

typedef __attribute__((ext_vector_type(8))) short short8;
typedef __attribute__((ext_vector_type(4))) short s4v;
typedef __attribute__((ext_vector_type(2))) uint uint2v;
typedef __attribute__((ext_vector_type(4))) uint uint4v;
typedef __attribute__((ext_vector_type(4))) float floatx4;

#define CCH   256
#define QSCALE 0.17677669529663687f  // 32^-0.5
#define LOG2E  1.4426950408889634f

__device__ __forceinline__ unsigned short f2bf(float f) {
    unsigned u = __float_as_uint(f);
    u = u + 0x7fffu + ((u >> 16) & 1u);
    return (unsigned short)(u >> 16);
}

// pack two fp32 -> bf16x2 with round-half-up: (u+0x8000)>>16, fused via v_perm
__device__ __forceinline__ uint pk2bf(float a, float b) {
    uint ua = __float_as_uint(a) + 0x8000u;
    uint ub = __float_as_uint(b) + 0x8000u;
    return __builtin_amdgcn_perm(ub, ua, 0x07060302u);
}

__device__ __forceinline__ void gl_lds16(const void* g, void* l) {
    __builtin_amdgcn_global_load_lds((const __attribute__((address_space(1))) void*)g,
                                     (__attribute__((address_space(3))) void*)l, 16, 0, 0);
}

// token (w*512+n) -> flat spatial offset (*CCH) in x/out with +4 cyclic shift
__device__ __forceinline__ int spatial_off(int token) {
    int w = token >> 9, n = token & 511;
    int wh = w >> 4, ww = (w >> 2) & 3, wd = w & 3;
    int h1 = n >> 6, w1 = (n >> 3) & 7, d1 = n & 7;
    int gh = (wh * 8 + h1 + 4) & 31;
    int gw = (ww * 8 + w1 + 4) & 31;
    int gd = (wd * 8 + d1 + 4) & 31;
    return ((gh * 32 + gw) * 32 + gd) * CCH;
}

// ---------------- fused preprocessing: xconv | wconv | pair_prep ----------------
__global__ __launch_bounds__(256) void prep(const float* __restrict__ x,
                                            const float* __restrict__ Wq,
                                            const float* __restrict__ Wp,
                                            const float* __restrict__ rpb,
                                            ushort* __restrict__ Xw,
                                            ushort* __restrict__ Wqb,
                                            ushort* __restrict__ Wpb,
                                            uint* __restrict__ Up) {
    int b = blockIdx.x;
    if (b < 4096) {
        int tid = b * 256 + threadIdx.x;   // 1048576
        int token = tid >> 5, c8 = (tid & 31) * 8;
        const float* src = x + spatial_off(token) + c8;
        float4 a = *(const float4*)src;
        float4 bb = *(const float4*)(src + 4);
        uint2v lo, hi;
        lo[0] = pk2bf(a.x, a.y);
        lo[1] = pk2bf(a.z, a.w);
        hi[0] = pk2bf(bb.x, bb.y);
        hi[1] = pk2bf(bb.z, bb.w);
        uint2v* dst = (uint2v*)(Xw + (size_t)token * 256 + c8);
        dst[0] = lo;
        dst[1] = hi;
    } else if (b < 5120) {
        int tid = (b - 4096) * 256 + threadIdx.x;   // 262144
        if (tid < 196608) {
            float s = (tid < 65536) ? (QSCALE * LOG2E) : 1.0f;
            Wqb[tid] = f2bf(Wq[tid] * s);
        } else {
            int i = tid - 196608;
            Wpb[i] = f2bf(Wp[i]);
        }
    } else {
        int tid = (b - 5120) * 256 + threadIdx.x;   // 27000
        if (tid >= 27000) return;
        int head = tid / 3375, idx = tid - head * 3375;
        uint lo = f2bf(rpb[idx * 8 + head] * LOG2E);
        uint hi = f2bf(rpb[(idx > 0 ? idx - 1 : 0) * 8 + head] * LOG2E);
        Up[tid] = lo | (hi << 16);
    }
}

// ---------------- MFMA GEMM: C[32768 x 768] = Xw @ Wqb^T -> Q/K/Vf ----------------
// V in K=16 A-fragment order; K in K=32 QK A-fragment order; Q row-major.
// Q/K epilogue: LDS-bounce transpose -> coalesced 16B packed stores.
__global__ __launch_bounds__(256) void gemm_qkv(
    const ushort* __restrict__ A,   // [32768][256] bf16
    const ushort* __restrict__ Bw,  // [768][256] bf16
    const float* __restrict__ bq,
    ushort* __restrict__ Q, ushort* __restrict__ K, ushort* __restrict__ Vf) {
    __shared__ short Sh[17408];     // main loop: As=Sh[0:8192], Bs=Sh[8192:16384]
                                    // epilogue:  128x136 bf16 tile (rows 16B-aligned)
    short* As = Sh;
    short* Bs = Sh + 8192;
    const int t = threadIdx.x;
    const int wv = t >> 6, lane = t & 63, quad = lane >> 4, col = lane & 15;
    const int m0 = blockIdx.y * 128, n0 = blockIdx.x * 128;
    const int wm = (wv & 1) * 64, wn = (wv >> 1) * 64;

    floatx4 zf = {0.f, 0.f, 0.f, 0.f};
    floatx4 acc[4][4];
#pragma unroll
    for (int i = 0; i < 4; ++i)
#pragma unroll
        for (int j = 0; j < 4; ++j) acc[i][j] = zf;

    for (int kk = 0; kk < 256; kk += 64) {
        __syncthreads();
#pragma unroll
        for (int i = 0; i < 4; ++i) {
            int s = i * 256 + t;
            int row = s >> 3, qs = s & 7;
            int qg = qs ^ (row & 7);
            gl_lds16(A + (size_t)(m0 + row) * 256 + kk + qg * 8,
                     As + (i * 256 + wv * 64) * 8);
        }
#pragma unroll
        for (int i = 0; i < 4; ++i) {
            int s = i * 256 + t;
            int row = s >> 3, qs = s & 7;
            int qg = qs ^ (row & 7);
            gl_lds16(Bw + (size_t)(n0 + row) * 256 + kk + qg * 8,
                     Bs + (i * 256 + wv * 64) * 8);
        }
        __syncthreads();
#pragma unroll
        for (int h = 0; h < 2; ++h) {
            short8 af[4], bf[4];
#pragma unroll
            for (int mi = 0; mi < 4; ++mi) {
                int row = wm + mi * 16 + col;
                af[mi] = *(const short8*)(As + (row * 8 + ((h * 4 + quad) ^ (row & 7))) * 8);
            }
#pragma unroll
            for (int ni = 0; ni < 4; ++ni) {
                int row = wn + ni * 16 + col;
                bf[ni] = *(const short8*)(Bs + (row * 8 + ((h * 4 + quad) ^ (row & 7))) * 8);
            }
#pragma unroll
            for (int mi = 0; mi < 4; ++mi)
#pragma unroll
                for (int ni = 0; ni < 4; ++ni)
                    acc[mi][ni] = __builtin_amdgcn_mfma_f32_16x16x32_bf16(af[mi], bf[ni], acc[mi][ni], 0, 0, 0);
        }
    }

    const int bx = blockIdx.x;   // 0,1: Q   2,3: K   4,5: V  (block-uniform)
    if (bx >= 4) {
        // ---- V: direct packed stores (fragment order already n-contiguous) ----
#pragma unroll
        for (int ni = 0; ni < 4; ++ni) {
            int j = n0 + wn + ni * 16 + col;
            int head = (j >> 5) & 7, hd = j & 31;
            float bias = bq[j];
            int h = hd >> 4, colv = hd & 15;
#pragma unroll
            for (int mi = 0; mi < 4; ++mi) {
                int mb = m0 + wm + mi * 16 + quad * 4;   // n&3 = r, contiguous
                int w = mb >> 9, n = mb & 511;
                size_t off = ((size_t)((w * 8 + head) * 64 + (n >> 4) * 2 + h) << 8)
                           + ((((n >> 2) & 3) * 16 + colv) << 2);
                uint2v pv;
                pv[0] = pk2bf(acc[mi][ni][0] + bias, acc[mi][ni][1] + bias);
                pv[1] = pk2bf(acc[mi][ni][2] + bias, acc[mi][ni][3] + bias);
                *(uint2v*)(Vf + off) = pv;
            }
        }
    } else {
        // ---- Q/K: LDS-bounce -> 8 coalesced 16B stores/thread ----
        __syncthreads();   // all waves done reading As/Bs
#pragma unroll
        for (int ni = 0; ni < 4; ++ni) {
            int j = n0 + wn + ni * 16 + col;
            int jloc = wn + ni * 16 + col;
            float bias = bq[j] * ((j < 256) ? (QSCALE * LOG2E) : 1.0f);
#pragma unroll
            for (int mi = 0; mi < 4; ++mi) {
                int rowb = wm + mi * 16 + quad * 4;
#pragma unroll
                for (int r = 0; r < 4; ++r)
                    Sh[(rowb + r) * 136 + jloc] = (short)f2bf(acc[mi][ni][r] + bias);
            }
        }
        __syncthreads();
        ushort* dst = (bx < 2) ? Q : K;
#pragma unroll
        for (int k8 = 0; k8 < 8; ++k8) {
            int chunk = k8 * 256 + t;        // 0..2047
            int row = chunk >> 4;            // 0..127
            int jl = (chunk & 15) * 8;       // 0..120
            int j = n0 + jl;
            int m = m0 + row;
            int w = m >> 9, n = m & 511;
            int head = (j >> 5) & 7, hd = j & 31;
            uint4v vv = *(const uint4v*)(Sh + row * 136 + jl);
            size_t off;
            if (bx < 2) {
                off = ((size_t)(w * 8 + head) * 512 + n) * 32 + hd;          // row-major
            } else {
                off = ((size_t)(w * 8 + head) << 14) + ((size_t)(n >> 4) << 9)
                    + (((hd >> 3) * 16 + (n & 15)) << 3);                    // frag order
            }
            *(uint4v*)(dst + off) = vv;
        }
    }
}

// ---------------- MFMA GEMM: out = Y @ Wpb^T + bp, scatter w/ reverse shift ----------
// Epilogue: LDS-bounce (2 half-tiles of 64 rows, 64x132 f32), each thread emits
// 16 coalesced dwordx4 stores instead of 64 scalar 4B scattered stores.
__global__ __launch_bounds__(256) void gemm_proj(
    const ushort* __restrict__ A,   // Y [32768][256] bf16
    const ushort* __restrict__ Bw,  // [256][256] bf16
    const float* __restrict__ bp,
    float* __restrict__ out) {
    __shared__ short As[128 * 64];
    __shared__ short Bs[128 * 64];
    __shared__ float Shf[64 * 132];  // 33KB bounce buffer (separate; total 65KB, 2/CU)
    const int t = threadIdx.x;
    const int wv = t >> 6, lane = t & 63, quad = lane >> 4, col = lane & 15;
    const int m0 = blockIdx.y * 128, n0 = blockIdx.x * 128;
    const int wm = (wv & 1) * 64, wn = (wv >> 1) * 64;

    floatx4 zf = {0.f, 0.f, 0.f, 0.f};
    floatx4 acc[4][4];
#pragma unroll
    for (int i = 0; i < 4; ++i)
#pragma unroll
        for (int j = 0; j < 4; ++j) acc[i][j] = zf;

    for (int kk = 0; kk < 256; kk += 64) {
        __syncthreads();
#pragma unroll
        for (int i = 0; i < 4; ++i) {
            int s = i * 256 + t;
            int row = s >> 3, qs = s & 7;
            int qg = qs ^ (row & 7);
            gl_lds16(A + (size_t)(m0 + row) * 256 + kk + qg * 8,
                     As + (i * 256 + wv * 64) * 8);
        }
#pragma unroll
        for (int i = 0; i < 4; ++i) {
            int s = i * 256 + t;
            int row = s >> 3, qs = s & 7;
            int qg = qs ^ (row & 7);
            gl_lds16(Bw + (size_t)(n0 + row) * 256 + kk + qg * 8,
                     Bs + (i * 256 + wv * 64) * 8);
        }
        __syncthreads();
#pragma unroll
        for (int h = 0; h < 2; ++h) {
            short8 af[4], bf[4];
#pragma unroll
            for (int mi = 0; mi < 4; ++mi) {
                int row = wm + mi * 16 + col;
                af[mi] = *(const short8*)(As + (row * 8 + ((h * 4 + quad) ^ (row & 7))) * 8);
            }
#pragma unroll
            for (int ni = 0; ni < 4; ++ni) {
                int row = wn + ni * 16 + col;
                bf[ni] = *(const short8*)(Bs + (row * 8 + ((h * 4 + quad) ^ (row & 7))) * 8);
            }
#pragma unroll
            for (int mi = 0; mi < 4; ++mi)
#pragma unroll
                for (int ni = 0; ni < 4; ++ni)
                    acc[mi][ni] = __builtin_amdgcn_mfma_f32_16x16x32_bf16(af[mi], bf[ni], acc[mi][ni], 0, 0, 0);
        }
    }

    // ---- epilogue: bounce 2 half-tiles (64 rows x 128 f32) through Shf ----
    float biasv[4];
#pragma unroll
    for (int ni = 0; ni < 4; ++ni) biasv[ni] = bp[n0 + wn + ni * 16 + col];

#pragma unroll
    for (int h2 = 0; h2 < 2; ++h2) {
        __syncthreads();                    // Shf free (prev half read / As reads done)
        if ((wv & 1) == h2) {               // waves owning rows [h2*64, h2*64+64)
#pragma unroll
            for (int ni = 0; ni < 4; ++ni) {
                int jloc = wn + ni * 16 + col;
#pragma unroll
                for (int mi = 0; mi < 4; ++mi) {
                    int rl = mi * 16 + quad * 4;     // local row 0..63
#pragma unroll
                    for (int r = 0; r < 4; ++r)
                        Shf[(rl + r) * 132 + jloc] = acc[mi][ni][r] + biasv[ni];
                }
            }
        }
        __syncthreads();
        // 4 threads per row; each stores 8 float4 (64B contiguous per 4-lane group)
        int row = t >> 2;                   // 0..63
        int m = m0 + h2 * 64 + row;
        float* ob = out + spatial_off(m) + n0 + (t & 3) * 4;
        const float* sb = Shf + row * 132 + (t & 3) * 4;
#pragma unroll
        for (int k = 0; k < 8; ++k)
            *(float4*)(ob + k * 16) = *(const float4*)(sb + k * 16);
    }
}

// ---------------- MFMA windowed attention (v8, best measured: 47.5us) ----------------
__global__ __launch_bounds__(512, 2) void attn_kernel(
    const ushort* __restrict__ Q, const ushort* __restrict__ K,
    const ushort* __restrict__ Vf, const uint* __restrict__ Up,
    ushort* __restrict__ Y) {
    __shared__ short Kl[512 * 32];       // QK A-fragment order (pre-permuted in global)
    __shared__ short Vs[64 * 256];       // PV A-fragment order (pre-permuted in global)
    __shared__ uint  Ul[3375];           // per-head rel-pos pair table (log2-scaled)

    const int t = threadIdx.x;
    const int bid = blockIdx.x;
    const int w = bid >> 3, head = bid & 7;
    const int wh = w >> 4, ww = (w >> 2) & 3, wd = w & 3;
    const int wv = t >> 6, lane = t & 63, quad = lane >> 4, col = lane & 15;

    const ushort* Kg = K + (size_t)(w * 8 + head) * 512 * 32;
    const ushort* Vg = Vf + (size_t)(w * 8 + head) * 512 * 32;
    const ushort* Qg = Q + (size_t)(w * 8 + head) * 512 * 32;

    // ---- stage K and V once (async direct-to-LDS, linear; 512 threads x 4 iters) ----
#pragma unroll
    for (int i = 0; i < 4; ++i) {
        gl_lds16(Kg + (size_t)(i * 512 + t) * 8, Kl + (i * 512 + wv * 64) * 8);
        gl_lds16(Vg + (size_t)(i * 512 + t) * 8, Vs + (i * 512 + wv * 64) * 8);
    }
    // ---- stage this head's pair table ----
    const uint* Uph = Up + head * 3375;
    for (int i = t; i < 3375; i += 512) Ul[i] = Uph[i];
    __syncthreads();

    const bool boundary = (wh == 3) | (ww == 3) | (wd == 3);
    floatx4 zf = {0.f, 0.f, 0.f, 0.f};

    for (int qs = 0; qs < 4; ++qs) {
        const int qt = wv * 4 + qs;
        const short8 qf = *(const short8*)(Qg + (size_t)(qt * 16 + col) * 32 + quad * 8);

        const int qrow = qt * 16 + col;
        const int qh = qrow >> 6, qw = (qrow >> 3) & 7, qd = qrow & 7;
        const int Base0 = ((qh + 7) * 15 + (qw + 7 - (quad >> 1))) * 15
                        + (qd - ((quad & 1) << 2) + 7);
        const int cq = ((wh == 3) ? (1 + ((qrow >> 8) & 1)) * 16 : 0)
                     + ((ww == 3) ? (1 + ((qrow >> 5) & 1)) * 4 : 0)
                     + ((wd == 3) ? (1 + ((qrow >> 2) & 1)) : 0);

        float rs = 0.f;
        floatx4 o0 = zf, o1 = zf;

        // ---- keys in 2 chunks of 256: acc[16] produced & consumed per chunk ----
        for (int c = 0; c < 2; ++c) {   // rolled: keeps register liveness low
            const short* KlC = Kl + c * 8192;
            const short* VsC = Vs + c * 8192;
            const int BaseC = Base0 - c * 900;
            const int ckh = (wh == 3) ? ((1 + c) * 16) : 0;

            floatx4 acc[16];
            // produce: S^T tiles with bias (and mask) preloaded into the C operand
#pragma unroll
            for (int tt = 0; tt < 16; ++tt) {
                const int Kt2 = ((tt >> 2) * 15 + (tt & 3) * 2) * 15;
                uint p0 = Ul[BaseC - Kt2];
                uint p1 = Ul[BaseC - Kt2 - 2];
                floatx4 cf;
                cf[0] = __uint_as_float(p0 << 16);
                cf[1] = __uint_as_float(p0 & 0xffff0000u);
                cf[2] = __uint_as_float(p1 << 16);
                cf[3] = __uint_as_float(p1 & 0xffff0000u);
                if (boundary) {
                    int ck = ckh
                           + ((ww == 3) ? (1 + ((tt >> 1) & 1)) * 4 : 0)
                           + ((wd == 3) ? (1 + (quad & 1)) : 0);
                    float madd = (cq == ck) ? 0.f : -144.269504f;  // -100*log2e
                    cf[0] += madd; cf[1] += madd; cf[2] += madd; cf[3] += madd;
                }
                short8 kf = *(const short8*)(KlC + tt * 512 + lane * 8);
                acc[tt] = __builtin_amdgcn_mfma_f32_16x16x32_bf16(kf, qf, cf, 0, 0, 0);
            }

            // consume: raw v_exp (scores already in log2 domain), pack, PV
#pragma unroll
            for (int tt = 0; tt < 16; ++tt) {
                float e0 = __builtin_amdgcn_exp2f(acc[tt][0]);
                float e1 = __builtin_amdgcn_exp2f(acc[tt][1]);
                float e2 = __builtin_amdgcn_exp2f(acc[tt][2]);
                float e3 = __builtin_amdgcn_exp2f(acc[tt][3]);
                rs += (e0 + e1) + (e2 + e3);
                uint2v pp;
                pp[0] = pk2bf(e0, e1);
                pp[1] = pk2bf(e2, e3);
                s4v pf = __builtin_bit_cast(s4v, pp);
                s4v v0 = *(const s4v*)(VsC + ((tt * 2 + 0) << 8) + lane * 4);
                s4v v1 = *(const s4v*)(VsC + ((tt * 2 + 1) << 8) + lane * 4);
                o0 = __builtin_amdgcn_mfma_f32_16x16x16bf16_1k(v0, pf, o0, 0, 0, 0);
                o1 = __builtin_amdgcn_mfma_f32_16x16x16bf16_1k(v1, pf, o1, 0, 0, 0);
            }
        }

        rs += __shfl_xor(rs, 16);
        rs += __shfl_xor(rs, 32);
        const float inv = __builtin_amdgcn_rcpf(rs);

        // ---- epilogue: O^T row=hd(quad*4+r), col=q(lane&15); two packed 8B stores ----
        int token = w * 512 + qt * 16 + col;
        ushort* Yb = Y + (size_t)token * 256 + head * 32 + quad * 4;
        uint2v y0, y1;
        y0[0] = pk2bf(o0[0] * inv, o0[1] * inv);
        y0[1] = pk2bf(o0[2] * inv, o0[3] * inv);
        y1[0] = pk2bf(o1[0] * inv, o1[1] * inv);
        y1[1] = pk2bf(o1[2] * inv, o1[3] * inv);
        *(uint2v*)(Yb) = y0;
        *(uint2v*)(Yb + 16) = y1;
    }
}

extern "C" void kernel_launch(void* const* d_in, const int* in_sizes, int n_in,
                              void* d_out, int out_size, void* d_ws, size_t ws_size,
                              hipStream_t stream) {
    const float* x      = (const float*)d_in[0];
    const float* qkv_w  = (const float*)d_in[1];
    const float* qkv_b  = (const float*)d_in[2];
    const float* proj_w = (const float*)d_in[3];
    const float* proj_b = (const float*)d_in[4];
    const float* rpb    = (const float*)d_in[5];
    float* out = (float*)d_out;

    // ws layout (ushorts): Xw 8.39M | Q 8.39M | K 8.39M | Vf 8.39M | Y 8.39M | Up 54K | Wqb | Wpb
    ushort* Xw  = (ushort*)d_ws;
    ushort* Q   = Xw + 8388608;
    ushort* K   = Q + 8388608;
    ushort* Vf  = K + 8388608;
    ushort* Y   = Vf + 8388608;
    uint*   Up  = (uint*)(Y + 8388608);
    ushort* Wqb = (ushort*)(Up + 27008);
    ushort* Wpb = Wqb + 196608;

    prep<<<dim3(5226), dim3(256), 0, stream>>>(x, qkv_w, proj_w, rpb, Xw, Wqb, Wpb, Up);
    gemm_qkv<<<dim3(6, 256), dim3(256), 0, stream>>>(Xw, Wqb, qkv_b, Q, K, Vf);
    attn_kernel<<<dim3(512), dim3(512), 0, stream>>>(Q, K, Vf, Up, Y);
    gemm_proj<<<dim3(2, 256), dim3(256), 0, stream>>>(Y, Wpb, proj_b, out);
}